// Round 4
// baseline (16498.901 us; speedup 1.0000x reference)
//
#include <hip/hip_runtime.h>

#define S_ 128

typedef __attribute__((ext_vector_type(8))) short short8;
typedef __attribute__((ext_vector_type(4))) float f32x4;
union U16x8 { uint4 u4; short8 s8; };

__device__ inline float bf2f(unsigned short u){
  unsigned int x = ((unsigned int)u) << 16;
  float f; __builtin_memcpy(&f, &x, 4); return f;
}
__device__ inline unsigned short f2bf(float f){
  unsigned int x; __builtin_memcpy(&x, &f, 4);
  x = x + 0x7FFFu + ((x >> 16) & 1u);
  return (unsigned short)(x >> 16);
}
__device__ inline void split8(float4 f0, float4 f1, uint4& hi, uint4& lo){
  float vv[8] = {f0.x,f0.y,f0.z,f0.w,f1.x,f1.y,f1.z,f1.w};
  unsigned int h[8], l[8];
  #pragma unroll
  for (int i = 0; i < 8; ++i){
    unsigned short hh = f2bf(vv[i]);
    h[i] = hh; l[i] = f2bf(vv[i] - bf2f(hh));
  }
  hi = (uint4){h[0]|(h[1]<<16), h[2]|(h[3]<<16), h[4]|(h[5]<<16), h[6]|(h[7]<<16)};
  lo = (uint4){l[0]|(l[1]<<16), l[2]|(l[3]<<16), l[4]|(l[5]<<16), l[6]|(l[7]<<16)};
}

__global__ __launch_bounds__(256)
void split_fp32(const float* __restrict__ x,
                unsigned short* __restrict__ hi,
                unsigned short* __restrict__ lo, int n4){
  int i = blockIdx.x * 256 + threadIdx.x;
  if (i >= n4) return;
  float4 v = ((const float4*)x)[i];
  ushort4 h, l;
  h.x = f2bf(v.x); l.x = f2bf(v.x - bf2f(h.x));
  h.y = f2bf(v.y); l.y = f2bf(v.y - bf2f(h.y));
  h.z = f2bf(v.z); l.z = f2bf(v.z - bf2f(h.z));
  h.w = f2bf(v.w); l.w = f2bf(v.w - bf2f(h.w));
  ((ushort4*)hi)[i] = h;
  ((ushort4*)lo)[i] = l;
}

// One RNN step, 2D decomposition: grid 256 = 8 kb x 32 nb (bx = nb*8 + kb).
// Block (kb,nb): partial[64x128] = 3-term bf16 emu of h(64 x k-slice512) * Whh(n-slice128 x k-slice)^T.
// Last-arriving block per nb reduces 8 partials, adds vx (fp32 exact), relu, writes h hi/lo + G.
__global__ __launch_bounds__(512, 2)
void step_phase(const unsigned short* __restrict__ hHi,
                const unsigned short* __restrict__ hLo,
                const unsigned short* __restrict__ WHi,
                const unsigned short* __restrict__ WLo,
                float* __restrict__ partial,
                unsigned int* __restrict__ cnt,
                const float* __restrict__ v,
                const float* __restrict__ Wih, int s,
                unsigned short* __restrict__ oHi,
                unsigned short* __restrict__ oLo,
                unsigned short* __restrict__ g)
{
  const int bx = blockIdx.x, kb = bx & 7, nb = bx >> 3;
  const int tid = threadIdx.x, lane = tid & 63, wave = tid >> 6;
  const int quad = lane >> 4, l16 = lane & 15;
  const int mw = wave & 3, nw = wave >> 2;
  __shared__ __attribute__((aligned(16))) unsigned short BH[2][128*40];
  __shared__ __attribute__((aligned(16))) unsigned short BL[2][128*40];
  __shared__ int lastFlag;
  const int srow = tid >> 2, sk = (tid & 3) << 3;
  const unsigned short* wHp = WHi + (size_t)(nb*128 + srow)*4096 + kb*512 + sk;
  const unsigned short* wLp = WLo + (size_t)(nb*128 + srow)*4096 + kb*512 + sk;
  const unsigned short* aHp = hHi + (size_t)(mw*16 + l16)*4096 + kb*512 + quad*8;
  const unsigned short* aLp = hLo + (size_t)(mw*16 + l16)*4096 + kb*512 + quad*8;
  uint4 wh[4], wl[4], ah[4], al[4];
  #pragma unroll
  for (int i = 0; i < 3; ++i){
    wh[i] = *(const uint4*)(wHp + i*32);
    wl[i] = *(const uint4*)(wLp + i*32);
    ah[i] = *(const uint4*)(aHp + i*32);
    al[i] = *(const uint4*)(aLp + i*32);
  }
  *(uint4*)&BH[0][srow*40 + sk] = wh[0];
  *(uint4*)&BL[0][srow*40 + sk] = wl[0];
  __syncthreads();
  f32x4 acc[4];
  #pragma unroll
  for (int tn = 0; tn < 4; ++tn) acc[tn] = (f32x4){0.f,0.f,0.f,0.f};
  for (int kc = 0; kc < 16; ++kc){
    const int cur = kc & 1;
    if (kc + 3 < 16){
      const int sl = (kc + 3) & 3;
      wh[sl] = *(const uint4*)(wHp + (kc+3)*32);
      wl[sl] = *(const uint4*)(wLp + (kc+3)*32);
      ah[sl] = *(const uint4*)(aHp + (kc+3)*32);
      al[sl] = *(const uint4*)(aLp + (kc+3)*32);
    }
    U16x8 aU, lU; aU.u4 = ah[kc & 3]; lU.u4 = al[kc & 3];
    #pragma unroll
    for (int tn = 0; tn < 4; ++tn){
      U16x8 bh, bl;
      const int off = (nw*64 + tn*16 + l16)*40 + quad*8;
      bh.u4 = *(const uint4*)&BH[cur][off];
      bl.u4 = *(const uint4*)&BL[cur][off];
      acc[tn] = __builtin_amdgcn_mfma_f32_16x16x32_bf16(aU.s8, bh.s8, acc[tn], 0, 0, 0);
      acc[tn] = __builtin_amdgcn_mfma_f32_16x16x32_bf16(aU.s8, bl.s8, acc[tn], 0, 0, 0);
      acc[tn] = __builtin_amdgcn_mfma_f32_16x16x32_bf16(lU.s8, bh.s8, acc[tn], 0, 0, 0);
    }
    if (kc + 1 < 16){
      const int ns = (kc + 1) & 3;
      *(uint4*)&BH[cur^1][srow*40 + sk] = wh[ns];
      *(uint4*)&BL[cur^1][srow*40 + sk] = wl[ns];
      __syncthreads();
    }
  }
  float* pb = partial + (size_t)(nb*8 + kb) * 8192;
  #pragma unroll
  for (int tn = 0; tn < 4; ++tn){
    const int col = nw*64 + tn*16 + l16;
    #pragma unroll
    for (int r = 0; r < 4; ++r){
      const int row = mw*16 + quad*4 + r;
      pb[row*128 + col] = acc[tn][r];
    }
  }
  __threadfence();
  __syncthreads();
  if (tid == 0){
    unsigned int old = atomicAdd(&cnt[nb], 1u);
    lastFlag = (old == 7u);
  }
  __syncthreads();
  if (!lastFlag) return;
  __threadfence();
  const float* pbase = partial + (size_t)nb * 8 * 8192;
  #pragma unroll
  for (int j = 0; j < 4; ++j){
    const int idx = tid*16 + j*4;
    float4 sum = {0.f,0.f,0.f,0.f};
    #pragma unroll
    for (int k2 = 0; k2 < 8; ++k2){
      float4 p = *(const float4*)(pbase + (size_t)k2*8192 + idx);
      sum.x += p.x; sum.y += p.y; sum.z += p.z; sum.w += p.w;
    }
    const int b = idx >> 7, noff = idx & 127, n = nb*128 + noff;
    const float2 vv = *(const float2*)(v + ((size_t)b*S_ + s)*2);
    float vals[4] = {sum.x, sum.y, sum.z, sum.w};
    ushort4 HH, LL;
    #pragma unroll
    for (int e = 0; e < 4; ++e){
      const float2 wi = *(const float2*)(Wih + (size_t)(n+e)*2);
      float val = vals[e] + vv.x*wi.x + vv.y*wi.y;
      val = fmaxf(val, 0.f);
      unsigned short hh2 = f2bf(val);
      ((unsigned short*)&HH)[e] = hh2;
      ((unsigned short*)&LL)[e] = f2bf(val - bf2f(hh2));
    }
    const size_t o = (size_t)b*4096 + n;
    *(ushort4*)(oHi + o) = HH;
    *(ushort4*)(oLo + o) = LL;
    *(ushort4*)(g   + o) = HH;
  }
}

// h0 = p0(64x512) @ Winit(4096x512)^T, 3-term, on-the-fly fp32->bf16 splits. 32 blocks.
__global__ __launch_bounds__(512, 2)
void h0_mm(const float* __restrict__ p0,
           const float* __restrict__ Wini,
           unsigned short* __restrict__ oHi,
           unsigned short* __restrict__ oLo)
{
  const int nb = blockIdx.x;
  const int tid = threadIdx.x, lane = tid & 63, wave = tid >> 6;
  const int quad = lane >> 4, l16 = lane & 15;
  const int mw = wave & 3, nw = wave >> 2;
  __shared__ __attribute__((aligned(16))) unsigned short BH[128*40];
  __shared__ __attribute__((aligned(16))) unsigned short BL[128*40];
  const int srow = tid >> 2, sk = (tid & 3) << 3;
  const float* wp = Wini + (size_t)(nb*128 + srow)*512 + sk;
  const float* ap = p0 + (size_t)(mw*16 + l16)*512 + quad*8;
  f32x4 acc[4];
  #pragma unroll
  for (int tn = 0; tn < 4; ++tn) acc[tn] = (f32x4){0.f,0.f,0.f,0.f};
  for (int kc = 0; kc < 16; ++kc){
    float4 f0 = *(const float4*)(wp + kc*32);
    float4 f1 = *(const float4*)(wp + kc*32 + 4);
    uint4 hi, lo; split8(f0, f1, hi, lo);
    __syncthreads();
    *(uint4*)&BH[srow*40 + sk] = hi;
    *(uint4*)&BL[srow*40 + sk] = lo;
    __syncthreads();
    float4 a0 = *(const float4*)(ap + kc*32);
    float4 a1 = *(const float4*)(ap + kc*32 + 4);
    uint4 ahi, alo; split8(a0, a1, ahi, alo);
    U16x8 aU, lU; aU.u4 = ahi; lU.u4 = alo;
    #pragma unroll
    for (int tn = 0; tn < 4; ++tn){
      U16x8 bh, bl;
      const int off = (nw*64 + tn*16 + l16)*40 + quad*8;
      bh.u4 = *(const uint4*)&BH[off];
      bl.u4 = *(const uint4*)&BL[off];
      acc[tn] = __builtin_amdgcn_mfma_f32_16x16x32_bf16(aU.s8, bh.s8, acc[tn], 0, 0, 0);
      acc[tn] = __builtin_amdgcn_mfma_f32_16x16x32_bf16(aU.s8, bl.s8, acc[tn], 0, 0, 0);
      acc[tn] = __builtin_amdgcn_mfma_f32_16x16x32_bf16(lU.s8, bh.s8, acc[tn], 0, 0, 0);
    }
  }
  #pragma unroll
  for (int tn = 0; tn < 4; ++tn){
    const int n = nb*128 + nw*64 + tn*16 + l16;
    #pragma unroll
    for (int r = 0; r < 4; ++r){
      const int row = mw*16 + quad*4 + r;
      float val = acc[tn][r];
      unsigned short hh = f2bf(val);
      oHi[(size_t)row*4096 + n] = hh;
      oLo[(size_t)row*4096 + n] = f2bf(val - bf2f(hh));
    }
  }
}

// out = G(len*64 x 4096, bf16 hi) @ Wdec(512x4096)^T, 2-term, Wdec split on the fly.
// grid (len, 8): block = (slot: 64 b-rows) x (64 p-cols); 256 thr = 4 waves (2x2 of 32x32).
__global__ __launch_bounds__(256, 2)
void decode_k(const unsigned short* __restrict__ G,
              const float* __restrict__ Wd,
              float* __restrict__ out, int s_base)
{
  const int slot = blockIdx.x, pb = blockIdx.y;
  const int tid = threadIdx.x, lane = tid & 63, wave = tid >> 6;
  const int quad = lane >> 4, l16 = lane & 15;
  const int wm = wave & 1, wn = wave >> 1;
  __shared__ __attribute__((aligned(16))) unsigned short AH[2][64*40];
  __shared__ __attribute__((aligned(16))) unsigned short BH[2][64*40];
  __shared__ __attribute__((aligned(16))) unsigned short BL[2][64*40];
  const int srow = tid >> 2, sk = (tid & 3) << 3;
  const unsigned short* gp = G + (size_t)slot*262144 + (size_t)srow*4096 + sk;
  const float* wp = Wd + (size_t)(pb*64 + srow)*4096 + sk;
  uint4 ga[4]; float4 w0[4], w1[4];
  #pragma unroll
  for (int i = 0; i < 3; ++i){
    ga[i] = *(const uint4*)(gp + i*32);
    w0[i] = *(const float4*)(wp + i*32);
    w1[i] = *(const float4*)(wp + i*32 + 4);
  }
  {
    uint4 hi, lo; split8(w0[0], w1[0], hi, lo);
    *(uint4*)&AH[0][srow*40 + sk] = ga[0];
    *(uint4*)&BH[0][srow*40 + sk] = hi;
    *(uint4*)&BL[0][srow*40 + sk] = lo;
  }
  __syncthreads();
  f32x4 acc[2][2];
  #pragma unroll
  for (int a = 0; a < 2; ++a)
    #pragma unroll
    for (int b = 0; b < 2; ++b) acc[a][b] = (f32x4){0.f,0.f,0.f,0.f};
  for (int kc = 0; kc < 128; ++kc){
    const int cur = kc & 1;
    if (kc + 3 < 128){
      const int sl = (kc + 3) & 3;
      ga[sl] = *(const uint4*)(gp + (size_t)(kc+3)*32);
      w0[sl] = *(const float4*)(wp + (size_t)(kc+3)*32);
      w1[sl] = *(const float4*)(wp + (size_t)(kc+3)*32 + 4);
    }
    U16x8 af[2], bh[2], bl[2];
    #pragma unroll
    for (int tm = 0; tm < 2; ++tm)
      af[tm].u4 = *(const uint4*)&AH[cur][(wm*32 + tm*16 + l16)*40 + quad*8];
    #pragma unroll
    for (int tn = 0; tn < 2; ++tn){
      bh[tn].u4 = *(const uint4*)&BH[cur][(wn*32 + tn*16 + l16)*40 + quad*8];
      bl[tn].u4 = *(const uint4*)&BL[cur][(wn*32 + tn*16 + l16)*40 + quad*8];
    }
    #pragma unroll
    for (int tm = 0; tm < 2; ++tm)
      #pragma unroll
      for (int tn = 0; tn < 2; ++tn){
        acc[tm][tn] = __builtin_amdgcn_mfma_f32_16x16x32_bf16(af[tm].s8, bh[tn].s8, acc[tm][tn], 0, 0, 0);
        acc[tm][tn] = __builtin_amdgcn_mfma_f32_16x16x32_bf16(af[tm].s8, bl[tn].s8, acc[tm][tn], 0, 0, 0);
      }
    if (kc + 1 < 128){
      const int ns = (kc + 1) & 3;
      uint4 hi, lo; split8(w0[ns], w1[ns], hi, lo);
      *(uint4*)&AH[cur^1][srow*40 + sk] = ga[ns];
      *(uint4*)&BH[cur^1][srow*40 + sk] = hi;
      *(uint4*)&BL[cur^1][srow*40 + sk] = lo;
      __syncthreads();
    }
  }
  const int s = s_base + slot;
  #pragma unroll
  for (int tm = 0; tm < 2; ++tm){
    #pragma unroll
    for (int tn = 0; tn < 2; ++tn){
      const int p = pb*64 + wn*32 + tn*16 + l16;
      #pragma unroll
      for (int r = 0; r < 4; ++r){
        const int b = wm*32 + tm*16 + quad*4 + r;
        out[((size_t)b*S_ + s)*512 + p] = acc[tm][tn][r];
      }
    }
  }
}

extern "C" void kernel_launch(void* const* d_in, const int* in_sizes, int n_in,
                              void* d_out, int out_size, void* d_ws, size_t ws_size,
                              hipStream_t stream) {
  const float* v    = (const float*)d_in[0];
  const float* p0   = (const float*)d_in[1];
  const float* Wini = (const float*)d_in[2];
  const float* Wih  = (const float*)d_in[3];
  const float* Whh  = (const float*)d_in[4];
  const float* Wdec = (const float*)d_in[5];
  float* out = (float*)d_out;
  char* wsb = (char*)d_ws;

  unsigned short* WhhHI = (unsigned short*)(wsb);                    // 32 MB
  unsigned short* WhhLO = (unsigned short*)(wsb + 33554432);         // 32 MB
  unsigned short* hHi[2] = { (unsigned short*)(wsb + 67108864),
                             (unsigned short*)(wsb + 67108864 + 524288) };
  unsigned short* hLo[2] = { (unsigned short*)(wsb + 68157440),
                             (unsigned short*)(wsb + 68157440 + 524288) };
  float*         partial  = (float*)(wsb + 69206016);                // 8 MB
  unsigned int*  counters = (unsigned int*)(wsb + 77594624);         // 16 KB
  unsigned short* Gbase   = (unsigned short*)(wsb + 77611008);       // slabs 512 KB

  long long Sc = ((long long)ws_size - 77611008LL) / 524288LL;
  if (Sc > 128) Sc = 128;
  if (Sc < 1) Sc = 1;

  split_fp32<<<dim3(16384), dim3(256), 0, stream>>>(Whh, WhhHI, WhhLO, 4194304);
  hipMemsetAsync(counters, 0, 128*32*4, stream);
  h0_mm<<<dim3(32), dim3(512), 0, stream>>>(p0, Wini, hHi[0], hLo[0]);

  int cur = 0, chunk_start = 0;
  for (int s = 0; s < 128; ++s){
    int nxt = cur ^ 1;
    int slot = s - chunk_start;
    step_phase<<<dim3(256), dim3(512), 0, stream>>>(
        hHi[cur], hLo[cur], WhhHI, WhhLO,
        partial, counters + s*32, v, Wih, s,
        hHi[nxt], hLo[nxt], Gbase + (size_t)slot * 262144);
    cur = nxt;
    if (slot + 1 == (int)Sc || s == 127){
      decode_k<<<dim3(slot + 1, 8), dim3(256), 0, stream>>>(Gbase, Wdec, out, chunk_start);
      chunk_start = s + 1;
    }
  }
}

// Round 5
// 12311.591 us; speedup vs baseline: 1.3401x; 1.3401x over previous
//
#include <hip/hip_runtime.h>

typedef __attribute__((ext_vector_type(8))) short short8;
typedef __attribute__((ext_vector_type(4))) float f32x4;
union U16x8 { uint4 u4; short8 s8; };

__device__ inline float bf2f(unsigned short u){
  unsigned int x = ((unsigned int)u) << 16;
  float f; __builtin_memcpy(&f, &x, 4); return f;
}
__device__ inline unsigned short f2bf(float f){
  unsigned int x; __builtin_memcpy(&x, &f, 4);
  x = x + 0x7FFFu + ((x >> 16) & 1u);
  return (unsigned short)(x >> 16);
}
__device__ inline void split4(float4 f, uint2& hi, uint2& lo){
  unsigned short h0=f2bf(f.x), h1=f2bf(f.y), h2=f2bf(f.z), h3=f2bf(f.w);
  unsigned short l0=f2bf(f.x-bf2f(h0)), l1=f2bf(f.y-bf2f(h1)),
                 l2=f2bf(f.z-bf2f(h2)), l3=f2bf(f.w-bf2f(h3));
  hi = (uint2){(unsigned)h0 | ((unsigned)h1<<16), (unsigned)h2 | ((unsigned)h3<<16)};
  lo = (uint2){(unsigned)l0 | ((unsigned)l1<<16), (unsigned)l2 | ((unsigned)l3<<16)};
}
__device__ inline void split8(float4 f0, float4 f1, uint4& hi, uint4& lo){
  uint2 h0,l0,h1,l1; split4(f0,h0,l0); split4(f1,h1,l1);
  hi = (uint4){h0.x,h0.y,h1.x,h1.y};
  lo = (uint4){l0.x,l0.y,l1.x,l1.y};
}

__global__ __launch_bounds__(256)
void split_fp32(const float* __restrict__ x,
                unsigned short* __restrict__ hi,
                unsigned short* __restrict__ lo, int n4){
  int i = blockIdx.x * 256 + threadIdx.x;
  if (i >= n4) return;
  float4 v = ((const float4*)x)[i];
  ushort4 h, l;
  h.x = f2bf(v.x); l.x = f2bf(v.x - bf2f(h.x));
  h.y = f2bf(v.y); l.y = f2bf(v.y - bf2f(h.y));
  h.z = f2bf(v.z); l.z = f2bf(v.z - bf2f(h.z));
  h.w = f2bf(v.w); l.w = f2bf(v.w - bf2f(h.w));
  ((ushort4*)hi)[i] = h;
  ((ushort4*)lo)[i] = l;
}

#define MFMA16(a,b,c) __builtin_amdgcn_mfma_f32_16x16x32_bf16((a).s8,(b).s8,(c),0,0,0)

// One RNN step. grid 256 = 8 kb x 32 nb (kb = bx&7 -> XCD-local h k-slice).
// Block: partial[64 x 128] = 3-term bf16 emu of h(64 x 512-kslice) * Whh^T slice.
// Whh read fp32, split hi/lo during LDS staging (XOR-swizzled, dbuf, 64 KB).
// Last-arriving block per nb reduces 8 partials, adds vx, relu, writes h + G.
__global__ __launch_bounds__(512, 1)
void step_k(const unsigned short* __restrict__ hHi,
            const unsigned short* __restrict__ hLo,
            const float* __restrict__ W,
            float* __restrict__ partial,
            unsigned int* __restrict__ cnt,
            const float* __restrict__ v,
            const float* __restrict__ Wih, int s,
            unsigned short* __restrict__ oHi,
            unsigned short* __restrict__ oLo,
            unsigned short* __restrict__ g)
{
  const int bx = blockIdx.x, kb = bx & 7, nb = bx >> 3;
  const int tid = threadIdx.x, lane = tid & 63, wave = tid >> 6;
  const int quad = lane >> 4, l16 = lane & 15;
  const int mw = wave & 3, nw = wave >> 2;
  __shared__ unsigned short WH[2][8192];   // 128 rows x 64 k, XOR-swizzled groups of 8
  __shared__ unsigned short WL[2][8192];

  const float* Wp = W + (size_t)(nb * 128) * 4096 + kb * 512;
  const unsigned short* aHp = hHi + (size_t)(mw*16 + l16)*4096 + kb*512 + quad*8;
  const unsigned short* aLp = hLo + (size_t)(mw*16 + l16)*4096 + kb*512 + quad*8;

  float4 wring[2][4];
  uint4 ahr[2][2], alr[2][2];

  #define LOADW(c, dst) { _Pragma("unroll") \
    for (int i=0;i<4;++i){ int q = tid + i*512, row = q>>4, kc4 = (q&15)<<2; \
      (dst)[i] = *(const float4*)(Wp + (size_t)row*4096 + (c)*64 + kc4); } }
  #define STOREW(buf, src) { _Pragma("unroll") \
    for (int i=0;i<4;++i){ int q = tid + i*512, row = q>>4, kc4 = (q&15)<<2; \
      int swz = row*64 + ((((kc4>>3) ^ (row&7)))<<3) + (kc4&7); \
      uint2 hi2, lo2; split4((src)[i], hi2, lo2); \
      *(uint2*)&WH[buf][swz] = hi2; *(uint2*)&WL[buf][swz] = lo2; } }
  #define LOADA(c, ah, al) { _Pragma("unroll") \
    for (int ki=0;ki<2;++ki){ (ah)[ki] = *(const uint4*)(aHp + (c)*64 + ki*32); \
                              (al)[ki] = *(const uint4*)(aLp + (c)*64 + ki*32); } }

  f32x4 acc[4];
  #pragma unroll
  for (int tn=0;tn<4;++tn) acc[tn] = (f32x4){0.f,0.f,0.f,0.f};

  LOADW(0, wring[0]); LOADA(0, ahr[0], alr[0]);
  STOREW(0, wring[0]);
  LOADW(1, wring[1]); LOADA(1, ahr[1], alr[1]);
  __syncthreads();

  for (int c = 0; c < 8; ++c){
    const int cur = c & 1;
    if (c + 2 < 8) LOADW(c+2, wring[cur]);
    #pragma unroll
    for (int ki=0;ki<2;++ki){
      U16x8 a, aL; a.u4 = ahr[cur][ki]; aL.u4 = alr[cur][ki];
      #pragma unroll
      for (int tn=0;tn<4;++tn){
        const int row = nw*64 + tn*16 + l16;
        const int addr = row*64 + ((((ki*4+quad) ^ (row&7)))<<3);
        U16x8 bh, bl;
        bh.u4 = *(const uint4*)&WH[cur][addr];
        bl.u4 = *(const uint4*)&WL[cur][addr];
        acc[tn] = MFMA16(a,  bh, acc[tn]);
        acc[tn] = MFMA16(a,  bl, acc[tn]);
        acc[tn] = MFMA16(aL, bh, acc[tn]);
      }
    }
    if (c + 2 < 8) LOADA(c+2, ahr[cur], alr[cur]);
    if (c + 1 < 8){
      STOREW(cur ^ 1, wring[cur ^ 1]);
      __syncthreads();
    }
  }

  float* pb = partial + (size_t)bx * 8192;
  #pragma unroll
  for (int tn=0;tn<4;++tn){
    const int col = nw*64 + tn*16 + l16;
    #pragma unroll
    for (int r=0;r<4;++r)
      pb[(mw*16 + quad*4 + r)*128 + col] = acc[tn][r];
  }
  __threadfence();
  __syncthreads();                       // all LDS + partial use done
  volatile int* flagp = (int*)&WH[0][0]; // reuse LDS for the flag
  if (tid == 0) *flagp = (atomicAdd(&cnt[nb], 1u) == 7u) ? 1 : 0;
  __syncthreads();
  if (!*flagp) return;
  __threadfence();
  const float* gbase = partial + (size_t)nb * 8 * 8192;
  #pragma unroll
  for (int j=0;j<4;++j){
    const int i4 = tid + j*512;
    float4 sum = {0.f,0.f,0.f,0.f};
    #pragma unroll
    for (int k2=0;k2<8;++k2){
      float4 p = *(const float4*)(gbase + (size_t)k2*8192 + (size_t)i4*4);
      sum.x += p.x; sum.y += p.y; sum.z += p.z; sum.w += p.w;
    }
    const int eidx = i4*4, b = eidx >> 7, noff = eidx & 127, n = nb*128 + noff;
    const float2 vv = *(const float2*)(v + ((size_t)b*128 + s)*2);
    const float4 wA = *(const float4*)(Wih + (size_t)n*2);
    const float4 wB = *(const float4*)(Wih + (size_t)n*2 + 4);
    float vals[4] = { sum.x + vv.x*wA.x + vv.y*wA.y,
                      sum.y + vv.x*wA.z + vv.y*wA.w,
                      sum.z + vv.x*wB.x + vv.y*wB.y,
                      sum.w + vv.x*wB.z + vv.y*wB.w };
    ushort4 HH, LL;
    #pragma unroll
    for (int e=0;e<4;++e){
      float val = fmaxf(vals[e], 0.f);
      unsigned short hh = f2bf(val);
      ((unsigned short*)&HH)[e] = hh;
      ((unsigned short*)&LL)[e] = f2bf(val - bf2f(hh));
    }
    const size_t o = (size_t)b*4096 + n;
    *(ushort4*)(oHi + o) = HH;
    *(ushort4*)(oLo + o) = LL;
    *(ushort4*)(g   + o) = HH;
  }
}

// h0 = p0(64x512) @ Winit(4096x512)^T, 3-term, on-the-fly splits. 32 blocks.
__global__ __launch_bounds__(512, 2)
void h0_mm(const float* __restrict__ p0,
           const float* __restrict__ Wini,
           unsigned short* __restrict__ oHi,
           unsigned short* __restrict__ oLo)
{
  const int nb = blockIdx.x;
  const int tid = threadIdx.x, lane = tid & 63, wave = tid >> 6;
  const int quad = lane >> 4, l16 = lane & 15;
  const int mw = wave & 3, nw = wave >> 2;
  __shared__ __attribute__((aligned(16))) unsigned short BH[128*40];
  __shared__ __attribute__((aligned(16))) unsigned short BL[128*40];
  const int srow = tid >> 2, sk = (tid & 3) << 3;
  const float* wp = Wini + (size_t)(nb*128 + srow)*512 + sk;
  const float* ap = p0 + (size_t)(mw*16 + l16)*512 + quad*8;
  f32x4 acc[4];
  #pragma unroll
  for (int tn = 0; tn < 4; ++tn) acc[tn] = (f32x4){0.f,0.f,0.f,0.f};
  for (int kc = 0; kc < 16; ++kc){
    float4 f0 = *(const float4*)(wp + kc*32);
    float4 f1 = *(const float4*)(wp + kc*32 + 4);
    uint4 hi, lo; split8(f0, f1, hi, lo);
    __syncthreads();
    *(uint4*)&BH[srow*40 + sk] = hi;
    *(uint4*)&BL[srow*40 + sk] = lo;
    __syncthreads();
    float4 a0 = *(const float4*)(ap + kc*32);
    float4 a1 = *(const float4*)(ap + kc*32 + 4);
    uint4 ahi, alo; split8(a0, a1, ahi, alo);
    U16x8 aU, lU; aU.u4 = ahi; lU.u4 = alo;
    #pragma unroll
    for (int tn = 0; tn < 4; ++tn){
      U16x8 bh, bl;
      const int off = (nw*64 + tn*16 + l16)*40 + quad*8;
      bh.u4 = *(const uint4*)&BH[off];
      bl.u4 = *(const uint4*)&BL[off];
      acc[tn] = MFMA16(aU, bh, acc[tn]);
      acc[tn] = MFMA16(aU, bl, acc[tn]);
      acc[tn] = MFMA16(lU, bh, acc[tn]);
    }
  }
  #pragma unroll
  for (int tn = 0; tn < 4; ++tn){
    const int n = nb*128 + nw*64 + tn*16 + l16;
    #pragma unroll
    for (int r = 0; r < 4; ++r){
      const int row = mw*16 + quad*4 + r;
      float val = acc[tn][r];
      unsigned short hh = f2bf(val);
      oHi[(size_t)row*4096 + n] = hh;
      oLo[(size_t)row*4096 + n] = f2bf(val - bf2f(hh));
    }
  }
}

// out = G(len*64 x 4096, hi-only, slot-major) @ Wdec^T (2-term, pre-split bf16).
// grid (len/4, 4): 256-row M-tile (4 slots) x 128-col N-tile. 512 thr = 8 waves
// (wm 4 x wn 2), wave tile 64x64. A direct-from-global (ring), W via swizzled dbuf LDS.
__global__ __launch_bounds__(512, 1)
void decode_m(const unsigned short* __restrict__ G,
              const unsigned short* __restrict__ WHi,
              const unsigned short* __restrict__ WLo,
              float* __restrict__ out, int s_base)
{
  const int tid = threadIdx.x, lane = tid & 63, wave = tid >> 6;
  const int quad = lane >> 4, l16 = lane & 15;
  const int wm = wave & 3, wn = wave >> 2;
  const int m0 = blockIdx.x * 256;
  const int n0 = blockIdx.y * 128;
  __shared__ unsigned short BH[2][8192];
  __shared__ unsigned short BL[2][8192];

  const unsigned short* ap[4];
  #pragma unroll
  for (int tm=0;tm<4;++tm){
    const int m = m0 + wm*64 + tm*16 + l16;
    ap[tm] = G + (size_t)(m>>6)*262144 + (size_t)(m&63)*4096 + quad*8;
  }
  #define LOADWD(c, h2, l2) { _Pragma("unroll") \
    for (int i=0;i<2;++i){ int q = tid + i*512, row = q>>3, kcol = (q&7)<<3; \
      (h2)[i] = *(const uint4*)(WHi + (size_t)(n0+row)*4096 + (size_t)(c)*64 + kcol); \
      (l2)[i] = *(const uint4*)(WLo + (size_t)(n0+row)*4096 + (size_t)(c)*64 + kcol); } }
  #define STOREWD(buf, h2, l2) { _Pragma("unroll") \
    for (int i=0;i<2;++i){ int q = tid + i*512, row = q>>3, kcol = (q&7)<<3; \
      int swz = row*64 + ((((kcol>>3) ^ (row&7)))<<3); \
      *(uint4*)&BH[buf][swz] = (h2)[i]; *(uint4*)&BL[buf][swz] = (l2)[i]; } }
  #define LOADA2(c, dst) { _Pragma("unroll") \
    for (int tm=0;tm<4;++tm){ _Pragma("unroll") \
      for (int ki=0;ki<2;++ki) (dst)[tm][ki] = *(const uint4*)(ap[tm] + (size_t)(c)*64 + ki*32); } }

  f32x4 acc[4][4];
  #pragma unroll
  for (int a=0;a<4;++a)
    #pragma unroll
    for (int b=0;b<4;++b) acc[a][b] = (f32x4){0.f,0.f,0.f,0.f};

  uint4 wh[2], wl[2];
  uint4 aring[2][4][2];
  LOADWD(0, wh, wl); STOREWD(0, wh, wl);
  LOADA2(0, aring[0]);
  LOADA2(1, aring[1]);
  LOADWD(1, wh, wl);
  __syncthreads();

  for (int c = 0; c < 64; ++c){
    const int cur = c & 1;
    #pragma unroll
    for (int ki=0;ki<2;++ki){
      U16x8 bh[4], bl[4];
      #pragma unroll
      for (int tn=0;tn<4;++tn){
        const int row = wn*64 + tn*16 + l16;
        const int addr = row*64 + ((((ki*4+quad) ^ (row&7)))<<3);
        bh[tn].u4 = *(const uint4*)&BH[cur][addr];
        bl[tn].u4 = *(const uint4*)&BL[cur][addr];
      }
      #pragma unroll
      for (int tm=0;tm<4;++tm){
        U16x8 a; a.u4 = aring[cur][tm][ki];
        #pragma unroll
        for (int tn=0;tn<4;++tn){
          acc[tm][tn] = MFMA16(a, bh[tn], acc[tm][tn]);
          acc[tm][tn] = MFMA16(a, bl[tn], acc[tm][tn]);
        }
      }
    }
    if (c + 2 < 64) LOADA2(c+2, aring[cur]);
    if (c + 1 < 64){
      STOREWD(cur ^ 1, wh, wl);
      if (c + 2 < 64) LOADWD(c+2, wh, wl);
      __syncthreads();
    }
  }
  #pragma unroll
  for (int tm=0;tm<4;++tm){
    const int mbase = m0 + wm*64 + tm*16;
    #pragma unroll
    for (int tn=0;tn<4;++tn){
      const int p = n0 + wn*64 + tn*16 + l16;
      #pragma unroll
      for (int r=0;r<4;++r){
        const int m = mbase + quad*4 + r;
        out[((size_t)(m & 63)*128 + (s_base + (m >> 6)))*512 + p] = acc[tm][tn][r];
      }
    }
  }
}

extern "C" void kernel_launch(void* const* d_in, const int* in_sizes, int n_in,
                              void* d_out, int out_size, void* d_ws, size_t ws_size,
                              hipStream_t stream) {
  const float* v    = (const float*)d_in[0];
  const float* p0   = (const float*)d_in[1];
  const float* Wini = (const float*)d_in[2];
  const float* Wih  = (const float*)d_in[3];
  const float* Whh  = (const float*)d_in[4];
  const float* Wdec = (const float*)d_in[5];
  float* out = (float*)d_out;
  char* wsb = (char*)d_ws;

  // ws layout (bytes)
  unsigned short* hHi[2] = { (unsigned short*)(wsb + 0),
                             (unsigned short*)(wsb + 524288) };
  unsigned short* hLo[2] = { (unsigned short*)(wsb + 1048576),
                             (unsigned short*)(wsb + 1572864) };
  float*          part   = (float*)(wsb + 2097152);            // 8 MB
  unsigned int*   cnt    = (unsigned int*)(wsb + 10485760);    // 16 KB
  unsigned short* WdH    = (unsigned short*)(wsb + 10502144);  // 4 MB
  unsigned short* WdL    = (unsigned short*)(wsb + 14696448);  // 4 MB
  const size_t G_OFF = 18890752;
  unsigned short* Gbase  = (unsigned short*)(wsb + G_OFF);     // slots of 512 KB

  long long slots = ((long long)ws_size - (long long)G_OFF) / 524288LL;
  if (slots > 128) slots = 128;
  slots &= ~3LL;                      // multiple of 4 (decode M-tile = 4 slots)
  if (slots < 4) slots = 4;
  const int Sc = (int)slots;

  hipMemsetAsync(cnt, 0, 128*32*sizeof(unsigned int), stream);
  split_fp32<<<dim3(2048), dim3(256), 0, stream>>>(Wdec, WdH, WdL, 524288);
  h0_mm<<<dim3(32), dim3(512), 0, stream>>>(p0, Wini, hHi[0], hLo[0]);

  int cur = 0, chunk_start = 0;
  for (int s = 0; s < 128; ++s){
    const int nxt = cur ^ 1;
    const int slot = s - chunk_start;
    step_k<<<dim3(256), dim3(512), 0, stream>>>(
        hHi[cur], hLo[cur], Whh, part, cnt + s*32, v, Wih, s,
        hHi[nxt], hLo[nxt], Gbase + (size_t)slot * 262144);
    cur = nxt;
    if (slot + 1 == Sc || s == 127){
      const int len = slot + 1;       // multiple of 4
      decode_m<<<dim3(len/4, 4), dim3(512), 0, stream>>>(
          Gbase, WdH, WdL, out, chunk_start);
      chunk_start = s + 1;
    }
  }
}

// Round 6
// 7979.837 us; speedup vs baseline: 2.0676x; 1.5428x over previous
//
#include <hip/hip_runtime.h>

typedef __attribute__((ext_vector_type(8))) short short8;
typedef __attribute__((ext_vector_type(4))) float f32x4;
union U16x8 { uint4 u4; short8 s8; };

__device__ inline float bf2f(unsigned short u){
  unsigned int x = ((unsigned int)u) << 16;
  float f; __builtin_memcpy(&f, &x, 4); return f;
}
__device__ inline unsigned short f2bf(float f){
  unsigned int x; __builtin_memcpy(&x, &f, 4);
  x = x + 0x7FFFu + ((x >> 16) & 1u);
  return (unsigned short)(x >> 16);
}
__device__ inline void split4(float4 f, uint2& hi, uint2& lo){
  unsigned short h0=f2bf(f.x), h1=f2bf(f.y), h2=f2bf(f.z), h3=f2bf(f.w);
  unsigned short l0=f2bf(f.x-bf2f(h0)), l1=f2bf(f.y-bf2f(h1)),
                 l2=f2bf(f.z-bf2f(h2)), l3=f2bf(f.w-bf2f(h3));
  hi = (uint2){(unsigned)h0 | ((unsigned)h1<<16), (unsigned)h2 | ((unsigned)h3<<16)};
  lo = (uint2){(unsigned)l0 | ((unsigned)l1<<16), (unsigned)l2 | ((unsigned)l3<<16)};
}
__device__ inline void split8(float4 f0, float4 f1, uint4& hi, uint4& lo){
  uint2 h0,l0,h1,l1; split4(f0,h0,l0); split4(f1,h1,l1);
  hi = (uint4){h0.x,h0.y,h1.x,h1.y};
  lo = (uint4){l0.x,l0.y,l1.x,l1.y};
}

#define MFMA16(a,b,c) __builtin_amdgcn_mfma_f32_16x16x32_bf16((a).s8,(b).s8,(c),0,0,0)

__global__ __launch_bounds__(256)
void split_fp32(const float* __restrict__ x,
                unsigned short* __restrict__ hi,
                unsigned short* __restrict__ lo, int n4){
  int i = blockIdx.x * 256 + threadIdx.x;
  if (i >= n4) return;
  float4 v = ((const float4*)x)[i];
  ushort4 h, l;
  h.x = f2bf(v.x); l.x = f2bf(v.x - bf2f(h.x));
  h.y = f2bf(v.y); l.y = f2bf(v.y - bf2f(h.y));
  h.z = f2bf(v.z); l.z = f2bf(v.z - bf2f(h.z));
  h.w = f2bf(v.w); l.w = f2bf(v.w - bf2f(h.w));
  ((ushort4*)hi)[i] = h;
  ((ushort4*)lo)[i] = l;
}

// h0 = p0(64x512) @ Winit(4096x512)^T, 3-term, on-the-fly splits. 32 blocks.
__global__ __launch_bounds__(512, 2)
void h0_mm(const float* __restrict__ p0,
           const float* __restrict__ Wini,
           unsigned short* __restrict__ oHi,
           unsigned short* __restrict__ oLo)
{
  const int nb = blockIdx.x;
  const int tid = threadIdx.x, lane = tid & 63, wave = tid >> 6;
  const int quad = lane >> 4, l16 = lane & 15;
  const int mw = wave & 3, nw = wave >> 2;
  __shared__ __attribute__((aligned(16))) unsigned short BH[128*40];
  __shared__ __attribute__((aligned(16))) unsigned short BL[128*40];
  const int srow = tid >> 2, sk = (tid & 3) << 3;
  const float* wp = Wini + (size_t)(nb*128 + srow)*512 + sk;
  const float* ap = p0 + (size_t)(mw*16 + l16)*512 + quad*8;
  f32x4 acc[4];
  #pragma unroll
  for (int tn = 0; tn < 4; ++tn) acc[tn] = (f32x4){0.f,0.f,0.f,0.f};
  for (int kc = 0; kc < 16; ++kc){
    float4 f0 = *(const float4*)(wp + kc*32);
    float4 f1 = *(const float4*)(wp + kc*32 + 4);
    uint4 hi, lo; split8(f0, f1, hi, lo);
    __syncthreads();
    *(uint4*)&BH[srow*40 + sk] = hi;
    *(uint4*)&BL[srow*40 + sk] = lo;
    __syncthreads();
    float4 a0 = *(const float4*)(ap + kc*32);
    float4 a1 = *(const float4*)(ap + kc*32 + 4);
    uint4 ahi, alo; split8(a0, a1, ahi, alo);
    U16x8 aU, lU; aU.u4 = ahi; lU.u4 = alo;
    #pragma unroll
    for (int tn = 0; tn < 4; ++tn){
      U16x8 bh, bl;
      const int off = (nw*64 + tn*16 + l16)*40 + quad*8;
      bh.u4 = *(const uint4*)&BH[off];
      bl.u4 = *(const uint4*)&BL[off];
      acc[tn] = MFMA16(aU, bh, acc[tn]);
      acc[tn] = MFMA16(aU, bl, acc[tn]);
      acc[tn] = MFMA16(lU, bh, acc[tn]);
    }
  }
  #pragma unroll
  for (int tn = 0; tn < 4; ++tn){
    const int n = nb*128 + nw*64 + tn*16 + l16;
    #pragma unroll
    for (int r = 0; r < 4; ++r){
      const int row = mw*16 + quad*4 + r;
      float val = acc[tn][r];
      unsigned short hh = f2bf(val);
      oHi[(size_t)row*4096 + n] = hh;
      oLo[(size_t)row*4096 + n] = f2bf(val - bf2f(hh));
    }
  }
}

// Persistent RNN: 256 blocks (8 kb x 32 nb) x 512 thr. W_hh hi+lo resident in
// VGPRs (128/thread). Per step: stage h k-slice to LDS, 192 MFMA, partial,
// grid barrier, distributed reduce(+vx,relu,split,h,G), grid barrier.
__global__ __launch_bounds__(512, 2)
void rnn_persist(const float* __restrict__ W,
                 const float* __restrict__ v,
                 const float* __restrict__ Wih,
                 unsigned short* __restrict__ hHi,
                 unsigned short* __restrict__ hLo,
                 float* __restrict__ partial,
                 unsigned int* __restrict__ bar,
                 unsigned short* __restrict__ G)
{
  const int bx = blockIdx.x, kb = bx & 7, nb = bx >> 3;
  const int tid = threadIdx.x, lane = tid & 63, wave = tid >> 6;
  const int quad = lane >> 4, l16 = lane & 15;
  __shared__ __attribute__((aligned(16))) unsigned short AH[64*512];  // 64 KB
  __shared__ __attribute__((aligned(16))) unsigned short AL[64*512];  // 64 KB

  // --- load this block's W slice into registers: wave owns n-tile `wave` (16 cols) ---
  uint4 whi[16], wlo[16];
  {
    const float* wp = W + (size_t)(nb*128 + wave*16 + l16)*4096 + kb*512 + quad*8;
    #pragma unroll
    for (int c = 0; c < 16; ++c){
      float4 f0 = *(const float4*)(wp + c*32);
      float4 f1 = *(const float4*)(wp + c*32 + 4);
      split8(f0, f1, whi[c], wlo[c]);
    }
  }

  const int redM = bx >> 2;                         // reduce: my m-row
  const int redN = ((bx & 3) << 10) + (tid << 1);   // my 2 n-cols

  for (int s = 0; s < 128; ++s){
    // ---- stage h k-slice (64 x 512, hi+lo) into swizzled LDS ----
    #pragma unroll
    for (int i = 0; i < 8; ++i){
      const int flat = tid + i*512;            // 0..4095
      const int row = flat >> 6, gk = flat & 63;
      const int phys = (gk & 56) | ((gk & 7) ^ (row & 7));
      const size_t src = (size_t)row*4096 + kb*512 + gk*8;
      *(uint4*)&AH[row*512 + phys*8] = *(const uint4*)(hHi + src);
      *(uint4*)&AL[row*512 + phys*8] = *(const uint4*)(hLo + src);
    }
    __syncthreads();

    f32x4 acc[4];
    #pragma unroll
    for (int mt = 0; mt < 4; ++mt) acc[mt] = (f32x4){0.f,0.f,0.f,0.f};
    #pragma unroll
    for (int c = 0; c < 16; ++c){
      U16x8 bh, bl; bh.u4 = whi[c]; bl.u4 = wlo[c];
      #pragma unroll
      for (int mt = 0; mt < 4; ++mt){
        const int row = mt*16 + l16;
        const int gk = c*4 + quad;
        const int phys = (gk & 56) | ((gk & 7) ^ (row & 7));
        U16x8 ah, al;
        ah.u4 = *(const uint4*)&AH[row*512 + phys*8];
        al.u4 = *(const uint4*)&AL[row*512 + phys*8];
        acc[mt] = MFMA16(ah, bh, acc[mt]);
        acc[mt] = MFMA16(ah, bl, acc[mt]);
        acc[mt] = MFMA16(al, bh, acc[mt]);
      }
    }

    // ---- write partial[kb][64][nb*128 + wave*16 + l16] ----
    {
      float* pb = partial + (size_t)(kb*64)*4096 + nb*128 + wave*16 + l16;
      #pragma unroll
      for (int mt = 0; mt < 4; ++mt)
        #pragma unroll
        for (int r = 0; r < 4; ++r)
          pb[(size_t)(mt*16 + quad*4 + r)*4096] = acc[mt][r];
    }

    // ---- grid barrier (release partials) ----
    __syncthreads();
    if (tid == 0){
      __threadfence();
      atomicAdd(&bar[2*s], 1u);
      while (__hip_atomic_load(&bar[2*s], __ATOMIC_RELAXED, __HIP_MEMORY_SCOPE_AGENT) < 256u)
        __builtin_amdgcn_s_sleep(1);
      __threadfence();
    }
    __syncthreads();

    // ---- distributed reduce: 1024 elems per block ----
    {
      float2 sum = {0.f, 0.f};
      #pragma unroll
      for (int k2 = 0; k2 < 8; ++k2){
        const float2 p = *(const float2*)(partial + (size_t)(k2*64 + redM)*4096 + redN);
        sum.x += p.x; sum.y += p.y;
      }
      const float2 vv = *(const float2*)(v + ((size_t)redM*128 + s)*2);
      const float4 wi = *(const float4*)(Wih + (size_t)redN*2);
      float v0 = fmaxf(sum.x + vv.x*wi.x + vv.y*wi.y, 0.f);
      float v1 = fmaxf(sum.y + vv.x*wi.z + vv.y*wi.w, 0.f);
      const unsigned short h0 = f2bf(v0), h1 = f2bf(v1);
      const unsigned short q0 = f2bf(v0 - bf2f(h0)), q1 = f2bf(v1 - bf2f(h1));
      const size_t o = (size_t)redM*4096 + redN;
      *(ushort2*)(hHi + o) = (ushort2){h0, h1};
      *(ushort2*)(hLo + o) = (ushort2){q0, q1};
      *(ushort2*)(G + (size_t)s*262144 + o) = (ushort2){h0, h1};
    }

    // ---- grid barrier (release new h) ----
    __syncthreads();
    if (tid == 0){
      __threadfence();
      atomicAdd(&bar[2*s+1], 1u);
      while (__hip_atomic_load(&bar[2*s+1], __ATOMIC_RELAXED, __HIP_MEMORY_SCOPE_AGENT) < 256u)
        __builtin_amdgcn_s_sleep(1);
      __threadfence();
    }
    __syncthreads();
  }
}

// out = G(8192 x 4096, hi-only) @ Wdec(512x4096)^T, 2-term (pre-split bf16).
// grid (64, 4), 256 thr = 4 waves (2x2), wave tile 64x64. A: dist-2 global ring.
// B: swizzled dbuf LDS, 64-k chunks.
__global__ __launch_bounds__(256, 1)
void decode_g(const unsigned short* __restrict__ G,
              const unsigned short* __restrict__ WdH,
              const unsigned short* __restrict__ WdL,
              float* __restrict__ out)
{
  const int tid = threadIdx.x, lane = tid & 63, wave = tid >> 6;
  const int quad = lane >> 4, l16 = lane & 15;
  const int wm = wave & 1, wn = wave >> 1;
  const int m0 = blockIdx.x * 128;
  const int n0 = blockIdx.y * 128;
  __shared__ __attribute__((aligned(16))) unsigned short BH[2][128*64];
  __shared__ __attribute__((aligned(16))) unsigned short BL[2][128*64];

  const unsigned short* gp[4];
  #pragma unroll
  for (int tm = 0; tm < 4; ++tm)
    gp[tm] = G + (size_t)(m0 + wm*64 + tm*16 + l16)*4096 + quad*8;

  #define LD_B(c, h4, l4) { _Pragma("unroll") \
    for (int i = 0; i < 4; ++i){ const int q = tid + i*256, row = q >> 3, gk = q & 7; \
      const size_t so = (size_t)(n0 + row)*4096 + (size_t)(c)*64 + gk*8; \
      (h4)[i] = *(const uint4*)(WdH + so); (l4)[i] = *(const uint4*)(WdL + so); } }
  #define ST_B(buf, h4, l4) { _Pragma("unroll") \
    for (int i = 0; i < 4; ++i){ const int q = tid + i*256, row = q >> 3, gk = q & 7; \
      const int phys = gk ^ (row & 7); \
      *(uint4*)&BH[buf][row*64 + phys*8] = (h4)[i]; \
      *(uint4*)&BL[buf][row*64 + phys*8] = (l4)[i]; } }
  #define LD_A(c, dst) { _Pragma("unroll") \
    for (int tm = 0; tm < 4; ++tm){ _Pragma("unroll") \
      for (int ks = 0; ks < 2; ++ks) \
        (dst)[tm][ks] = *(const uint4*)(gp[tm] + (size_t)(c)*64 + ks*32); } }

  f32x4 acc[4][4];
  #pragma unroll
  for (int a = 0; a < 4; ++a)
    #pragma unroll
    for (int b = 0; b < 4; ++b) acc[a][b] = (f32x4){0.f,0.f,0.f,0.f};

  uint4 pbh[4], pbl[4];
  uint4 ar[2][4][2];
  LD_B(0, pbh, pbl); ST_B(0, pbh, pbl);
  LD_A(0, ar[0]);
  LD_A(1, ar[1]);
  LD_B(1, pbh, pbl);
  __syncthreads();

  for (int c = 0; c < 64; ++c){
    const int cur = c & 1;
    #pragma unroll
    for (int ks = 0; ks < 2; ++ks){
      U16x8 bh[4], bl[4];
      #pragma unroll
      for (int tn = 0; tn < 4; ++tn){
        const int row = wn*64 + tn*16 + l16;
        const int gk = ks*4 + quad;
        const int phys = gk ^ (row & 7);
        bh[tn].u4 = *(const uint4*)&BH[cur][row*64 + phys*8];
        bl[tn].u4 = *(const uint4*)&BL[cur][row*64 + phys*8];
      }
      #pragma unroll
      for (int tm = 0; tm < 4; ++tm){
        U16x8 a; a.u4 = ar[cur][tm][ks];
        #pragma unroll
        for (int tn = 0; tn < 4; ++tn){
          acc[tm][tn] = MFMA16(a, bh[tn], acc[tm][tn]);
          acc[tm][tn] = MFMA16(a, bl[tn], acc[tm][tn]);
        }
      }
    }
    if (c + 2 < 64) LD_A(c+2, ar[cur]);
    if (c + 1 < 64){
      ST_B(cur ^ 1, pbh, pbl);
      if (c + 2 < 64) LD_B(c+2, pbh, pbl);
      __syncthreads();
    }
  }
  #pragma unroll
  for (int tm = 0; tm < 4; ++tm){
    #pragma unroll
    for (int tn = 0; tn < 4; ++tn){
      const int p = n0 + wn*64 + tn*16 + l16;
      #pragma unroll
      for (int r = 0; r < 4; ++r){
        const int rm = m0 + wm*64 + tm*16 + quad*4 + r;
        out[((size_t)(rm & 63)*128 + (rm >> 6))*512 + p] = acc[tm][tn][r];
      }
    }
  }
}

extern "C" void kernel_launch(void* const* d_in, const int* in_sizes, int n_in,
                              void* d_out, int out_size, void* d_ws, size_t ws_size,
                              hipStream_t stream) {
  const float* v    = (const float*)d_in[0];
  const float* p0   = (const float*)d_in[1];
  const float* Wini = (const float*)d_in[2];
  const float* Wih  = (const float*)d_in[3];
  const float* Whh  = (const float*)d_in[4];
  const float* Wdec = (const float*)d_in[5];
  float* out = (float*)d_out;
  char* wsb = (char*)d_ws;

  // ws layout (bytes): bar 4K | hHi 512K | hLo 512K | partial 8M | WdH 4M | WdL 4M | G 64M
  unsigned int*   bar  = (unsigned int*)(wsb + 0);
  unsigned short* hHi  = (unsigned short*)(wsb + 4096);
  unsigned short* hLo  = (unsigned short*)(wsb + 4096 + 524288);
  float*          part = (float*)(wsb + 1052672);
  unsigned short* WdH  = (unsigned short*)(wsb + 9441280);
  unsigned short* WdL  = (unsigned short*)(wsb + 13635584);
  unsigned short* G    = (unsigned short*)(wsb + 17829888);
  // end = 17829888 + 67108864 = 84938752 bytes (~81 MB)

  hipMemsetAsync(bar, 0, 4096, stream);
  split_fp32<<<dim3(2048), dim3(256), 0, stream>>>(Wdec, WdH, WdL, 524288);
  h0_mm<<<dim3(32), dim3(512), 0, stream>>>(p0, Wini, hHi, hLo);
  rnn_persist<<<dim3(256), dim3(512), 0, stream>>>(Whh, v, Wih, hHi, hLo, part, bar, G);
  decode_g<<<dim3(64, 4), dim3(256), 0, stream>>>(G, WdH, WdL, out);
}

// Round 7
// 3606.121 us; speedup vs baseline: 4.5752x; 2.2129x over previous
//
#include <hip/hip_runtime.h>

typedef __attribute__((ext_vector_type(8))) short short8;
typedef __attribute__((ext_vector_type(4))) float f32x4;
union U16x8 { uint4 u4; short8 s8; };

__device__ inline float bf2f(unsigned short u){
  unsigned int x = ((unsigned int)u) << 16;
  float f; __builtin_memcpy(&f, &x, 4); return f;
}
__device__ inline unsigned short f2bf(float f){
  unsigned int x; __builtin_memcpy(&x, &f, 4);
  x = x + 0x7FFFu + ((x >> 16) & 1u);
  return (unsigned short)(x >> 16);
}
__device__ inline void split4(float4 f, uint2& hi, uint2& lo){
  unsigned short h0=f2bf(f.x), h1=f2bf(f.y), h2=f2bf(f.z), h3=f2bf(f.w);
  unsigned short l0=f2bf(f.x-bf2f(h0)), l1=f2bf(f.y-bf2f(h1)),
                 l2=f2bf(f.z-bf2f(h2)), l3=f2bf(f.w-bf2f(h3));
  hi = (uint2){(unsigned)h0 | ((unsigned)h1<<16), (unsigned)h2 | ((unsigned)h3<<16)};
  lo = (uint2){(unsigned)l0 | ((unsigned)l1<<16), (unsigned)l2 | ((unsigned)l3<<16)};
}
__device__ inline void split8(float4 f0, float4 f1, uint4& hi, uint4& lo){
  uint2 h0,l0,h1,l1; split4(f0,h0,l0); split4(f1,h1,l1);
  hi = (uint4){h0.x,h0.y,h1.x,h1.y};
  lo = (uint4){l0.x,l0.y,l1.x,l1.y};
}

#define MFMA16(a,b,c) __builtin_amdgcn_mfma_f32_16x16x32_bf16((a).s8,(b).s8,(c),0,0,0)

// device-scope (sc1) fine-grained ops — cross-XCD coherent without cache flushes
__device__ inline void st_f32_sc(float* p, float v){
  __hip_atomic_store(p, v, __ATOMIC_RELAXED, __HIP_MEMORY_SCOPE_AGENT);
}
__device__ inline void st_u32_sc(unsigned int* p, unsigned int v){
  __hip_atomic_store(p, v, __ATOMIC_RELAXED, __HIP_MEMORY_SCOPE_AGENT);
}
__device__ inline unsigned long long ld_u64_sc(const unsigned long long* p){
  return __hip_atomic_load(p, __ATOMIC_RELAXED, __HIP_MEMORY_SCOPE_AGENT);
}
__device__ inline uint4 ld_b128_sc(const unsigned short* p){
  uint4 r;
  asm volatile("global_load_dwordx4 %0, %1, off sc0 sc1"
               : "=&v"(r) : "v"(p) : "memory");
  return r;
}
__device__ inline void wait_vm0(){ asm volatile("s_waitcnt vmcnt(0)" ::: "memory"); }

__global__ __launch_bounds__(256)
void split_fp32(const float* __restrict__ x,
                unsigned short* __restrict__ hi,
                unsigned short* __restrict__ lo, int n4){
  int i = blockIdx.x * 256 + threadIdx.x;
  if (i >= n4) return;
  float4 v = ((const float4*)x)[i];
  ushort4 h, l;
  h.x = f2bf(v.x); l.x = f2bf(v.x - bf2f(h.x));
  h.y = f2bf(v.y); l.y = f2bf(v.y - bf2f(h.y));
  h.z = f2bf(v.z); l.z = f2bf(v.z - bf2f(h.z));
  h.w = f2bf(v.w); l.w = f2bf(v.w - bf2f(h.w));
  ((ushort4*)hi)[i] = h;
  ((ushort4*)lo)[i] = l;
}

// h0 = p0(64x512) @ Winit(4096x512)^T, 3-term. Writes h in SWIZZLED global layout.
__global__ __launch_bounds__(512, 2)
void h0_mm(const float* __restrict__ p0,
           const float* __restrict__ Wini,
           unsigned short* __restrict__ oHi,
           unsigned short* __restrict__ oLo)
{
  const int nb = blockIdx.x;
  const int tid = threadIdx.x, lane = tid & 63, wave = tid >> 6;
  const int quad = lane >> 4, l16 = lane & 15;
  const int mw = wave & 3, nw = wave >> 2;
  __shared__ __attribute__((aligned(16))) unsigned short BH[128*40];
  __shared__ __attribute__((aligned(16))) unsigned short BL[128*40];
  const int srow = tid >> 2, sk = (tid & 3) << 3;
  const float* wp = Wini + (size_t)(nb*128 + srow)*512 + sk;
  const float* ap = p0 + (size_t)(mw*16 + l16)*512 + quad*8;
  f32x4 acc[4];
  #pragma unroll
  for (int tn = 0; tn < 4; ++tn) acc[tn] = (f32x4){0.f,0.f,0.f,0.f};
  for (int kc = 0; kc < 16; ++kc){
    float4 f0 = *(const float4*)(wp + kc*32);
    float4 f1 = *(const float4*)(wp + kc*32 + 4);
    uint4 hi, lo; split8(f0, f1, hi, lo);
    __syncthreads();
    *(uint4*)&BH[srow*40 + sk] = hi;
    *(uint4*)&BL[srow*40 + sk] = lo;
    __syncthreads();
    float4 a0 = *(const float4*)(ap + kc*32);
    float4 a1 = *(const float4*)(ap + kc*32 + 4);
    uint4 ahi, alo; split8(a0, a1, ahi, alo);
    U16x8 aU, lU; aU.u4 = ahi; lU.u4 = alo;
    #pragma unroll
    for (int tn = 0; tn < 4; ++tn){
      U16x8 bh, bl;
      const int off = (nw*64 + tn*16 + l16)*40 + quad*8;
      bh.u4 = *(const uint4*)&BH[off];
      bl.u4 = *(const uint4*)&BL[off];
      acc[tn] = MFMA16(aU, bh, acc[tn]);
      acc[tn] = MFMA16(aU, bl, acc[tn]);
      acc[tn] = MFMA16(lU, bh, acc[tn]);
    }
  }
  #pragma unroll
  for (int tn = 0; tn < 4; ++tn){
    const int n = nb*128 + nw*64 + tn*16 + l16;
    #pragma unroll
    for (int r = 0; r < 4; ++r){
      const int row = mw*16 + quad*4 + r;
      const int g = n >> 3, gp = (g & ~7) | ((g & 7) ^ (row & 7));
      const int np = (gp << 3) | (n & 7);
      float val = acc[tn][r];
      unsigned short hh = f2bf(val);
      oHi[(size_t)row*4096 + np] = hh;
      oLo[(size_t)row*4096 + np] = f2bf(val - bf2f(hh));
    }
  }
}

// Persistent RNN: 256 blocks (kb=bx&7, nb=bx>>3) x 512 thr. W hi/lo in VGPRs.
// Per step: sc1-stage h slice -> LDS, 192 MFMA, sc1 partial store, tree barrier,
// distributed reduce (+vx, relu, split, sc1 h write, nt G write), tree barrier.
__global__ __launch_bounds__(512, 2)
void rnn_persist(const float* __restrict__ W,
                 const float* __restrict__ v,
                 const float* __restrict__ Wih,
                 unsigned short* __restrict__ hHiA,
                 unsigned short* __restrict__ hLoA,
                 unsigned short* __restrict__ hHiB,
                 unsigned short* __restrict__ hLoB,
                 float* __restrict__ part,
                 unsigned int* __restrict__ bar,
                 unsigned short* __restrict__ G)
{
  const int bx = blockIdx.x, kb = bx & 7, nb = bx >> 3;
  const int tid = threadIdx.x, lane = tid & 63, wave = tid >> 6;
  const int quad = lane >> 4, l16 = lane & 15;
  __shared__ __attribute__((aligned(16))) unsigned short AH[64*512];  // 64 KB
  __shared__ __attribute__((aligned(16))) unsigned short AL[64*512];  // 64 KB

  unsigned int* sub1 = bar;          // [128][8]
  unsigned int* root1 = bar + 1024;  // [128]
  unsigned int* sub2 = bar + 2048;   // [128][8]
  unsigned int* root2 = bar + 3072;  // [128]

  // W slice -> registers: wave owns 16 cols (nb*128 + wave*16 + l16), k-slice kb*512
  uint4 whi[16], wlo[16];
  {
    const float* wp = W + (size_t)(nb*128 + wave*16 + l16)*4096 + kb*512 + quad*8;
    #pragma unroll
    for (int c = 0; c < 16; ++c){
      float4 f0 = *(const float4*)(wp + c*32);
      float4 f1 = *(const float4*)(wp + c*32 + 4);
      split8(f0, f1, whi[c], wlo[c]);
    }
  }

  const int redM = bx >> 2;
  const int nbase = ((bx & 3) << 10) + (tid << 1);

  for (int s = 0; s < 128; ++s){
    const unsigned short* hH = (s & 1) ? hHiB : hHiA;
    const unsigned short* hL = (s & 1) ? hLoB : hLoA;
    unsigned short* nHi = (s & 1) ? hHiA : hHiB;
    unsigned short* nLo = (s & 1) ? hLoA : hLoB;

    // ---- stage h k-slice (swizzled-global verbatim copy) via sc1 b128 loads ----
    {
      uint4 stg[8];
      #pragma unroll
      for (int i = 0; i < 8; ++i){
        const int flat = tid + i*512, row = flat >> 6, g = flat & 63;
        stg[i] = ld_b128_sc(hH + (size_t)row*4096 + (kb << 9) + g*8);
      }
      wait_vm0();
      #pragma unroll
      for (int i = 0; i < 8; ++i){
        const int flat = tid + i*512, row = flat >> 6, g = flat & 63;
        *(uint4*)&AH[row*512 + g*8] = stg[i];
      }
      #pragma unroll
      for (int i = 0; i < 8; ++i){
        const int flat = tid + i*512, row = flat >> 6, g = flat & 63;
        stg[i] = ld_b128_sc(hL + (size_t)row*4096 + (kb << 9) + g*8);
      }
      wait_vm0();
      #pragma unroll
      for (int i = 0; i < 8; ++i){
        const int flat = tid + i*512, row = flat >> 6, g = flat & 63;
        *(uint4*)&AL[row*512 + g*8] = stg[i];
      }
    }
    __syncthreads();

    // ---- MFMA: 16 k-chunks x 4 m-tiles x 3 terms ----
    f32x4 acc[4];
    #pragma unroll
    for (int mt = 0; mt < 4; ++mt) acc[mt] = (f32x4){0.f,0.f,0.f,0.f};
    #pragma unroll
    for (int c = 0; c < 16; ++c){
      U16x8 bh, bl; bh.u4 = whi[c]; bl.u4 = wlo[c];
      #pragma unroll
      for (int mt = 0; mt < 4; ++mt){
        const int row = mt*16 + l16;
        const int gk = c*4 + quad;
        const int phys = (gk & 56) | ((gk & 7) ^ (row & 7));
        U16x8 ah, al;
        ah.u4 = *(const uint4*)&AH[row*512 + phys*8];
        al.u4 = *(const uint4*)&AL[row*512 + phys*8];
        acc[mt] = MFMA16(ah, bh, acc[mt]);
        acc[mt] = MFMA16(ah, bl, acc[mt]);
        acc[mt] = MFMA16(al, bh, acc[mt]);
      }
    }

    // ---- partial store (sc1 write-through): tile layout [bx][w][m][c16] ----
    {
      float* pb = part + (size_t)bx*8192 + wave*1024 + l16;
      #pragma unroll
      for (int mt = 0; mt < 4; ++mt)
        #pragma unroll
        for (int r = 0; r < 4; ++r)
          st_f32_sc(pb + (mt*16 + quad*4 + r)*16, acc[mt][r]);
    }
    wait_vm0();
    __syncthreads();
    if (tid == 0){
      if (atomicAdd(&sub1[s*8 + kb], 1u) == 31u) atomicAdd(&root1[s], 1u);
      while (__hip_atomic_load(&root1[s], __ATOMIC_RELAXED, __HIP_MEMORY_SCOPE_AGENT) < 8u)
        __builtin_amdgcn_s_sleep(1);
    }
    __syncthreads();

    // ---- distributed reduce: 2 elems/thread (row redM, cols nbase, nbase+1) ----
    {
      float2 sum = {0.f, 0.f};
      const size_t off = (size_t)((nbase >> 4) & 7)*1024 + redM*16 + (nbase & 15);
      #pragma unroll
      for (int k2 = 0; k2 < 8; ++k2){
        unsigned long long q = ld_u64_sc((const unsigned long long*)
            (part + (size_t)((nbase >> 7)*8 + k2)*8192 + off));
        float2 p; __builtin_memcpy(&p, &q, 8);
        sum.x += p.x; sum.y += p.y;
      }
      const float2 vv = *(const float2*)(v + ((size_t)redM*128 + s)*2);
      const float4 wi = *(const float4*)(Wih + (size_t)nbase*2);
      float v0 = fmaxf(sum.x + vv.x*wi.x + vv.y*wi.y, 0.f);
      float v1 = fmaxf(sum.y + vv.x*wi.z + vv.y*wi.w, 0.f);
      const unsigned short h0 = f2bf(v0), h1 = f2bf(v1);
      const unsigned short q0 = f2bf(v0 - bf2f(h0)), q1 = f2bf(v1 - bf2f(h1));
      const int g = nbase >> 3, gp = (g & ~7) | ((g & 7) ^ (redM & 7));
      const int np = (gp << 3) | (nbase & 7);
      st_u32_sc((unsigned int*)(nHi + (size_t)redM*4096 + np),
                (unsigned)h0 | ((unsigned)h1 << 16));
      st_u32_sc((unsigned int*)(nLo + (size_t)redM*4096 + np),
                (unsigned)q0 | ((unsigned)q1 << 16));
      __builtin_nontemporal_store((unsigned)h0 | ((unsigned)h1 << 16),
          (unsigned int*)(G + (size_t)s*262144 + (size_t)redM*4096 + nbase));
    }
    wait_vm0();
    __syncthreads();
    if (tid == 0){
      if (atomicAdd(&sub2[s*8 + kb], 1u) == 31u) atomicAdd(&root2[s], 1u);
      while (__hip_atomic_load(&root2[s], __ATOMIC_RELAXED, __HIP_MEMORY_SCOPE_AGENT) < 8u)
        __builtin_amdgcn_s_sleep(1);
    }
    __syncthreads();
  }
}

// out = G(8192 x 4096, hi-only) @ Wdec(512x4096)^T, 2-term (pre-split bf16).
__global__ __launch_bounds__(256, 1)
void decode_g(const unsigned short* __restrict__ G,
              const unsigned short* __restrict__ WdH,
              const unsigned short* __restrict__ WdL,
              float* __restrict__ out)
{
  const int tid = threadIdx.x, lane = tid & 63, wave = tid >> 6;
  const int quad = lane >> 4, l16 = lane & 15;
  const int wm = wave & 1, wn = wave >> 1;
  const int m0 = blockIdx.x * 128;
  const int n0 = blockIdx.y * 128;
  __shared__ __attribute__((aligned(16))) unsigned short BH[2][128*64];
  __shared__ __attribute__((aligned(16))) unsigned short BL[2][128*64];

  const unsigned short* gp[4];
  #pragma unroll
  for (int tm = 0; tm < 4; ++tm)
    gp[tm] = G + (size_t)(m0 + wm*64 + tm*16 + l16)*4096 + quad*8;

  #define LD_B(c, h4, l4) { _Pragma("unroll") \
    for (int i = 0; i < 4; ++i){ const int q = tid + i*256, row = q >> 3, gk = q & 7; \
      const size_t so = (size_t)(n0 + row)*4096 + (size_t)(c)*64 + gk*8; \
      (h4)[i] = *(const uint4*)(WdH + so); (l4)[i] = *(const uint4*)(WdL + so); } }
  #define ST_B(buf, h4, l4) { _Pragma("unroll") \
    for (int i = 0; i < 4; ++i){ const int q = tid + i*256, row = q >> 3, gk = q & 7; \
      const int phys = gk ^ (row & 7); \
      *(uint4*)&BH[buf][row*64 + phys*8] = (h4)[i]; \
      *(uint4*)&BL[buf][row*64 + phys*8] = (l4)[i]; } }
  #define LD_A(c, dst) { _Pragma("unroll") \
    for (int tm = 0; tm < 4; ++tm){ _Pragma("unroll") \
      for (int ks = 0; ks < 2; ++ks) \
        (dst)[tm][ks] = *(const uint4*)(gp[tm] + (size_t)(c)*64 + ks*32); } }

  f32x4 acc[4][4];
  #pragma unroll
  for (int a = 0; a < 4; ++a)
    #pragma unroll
    for (int b = 0; b < 4; ++b) acc[a][b] = (f32x4){0.f,0.f,0.f,0.f};

  uint4 pbh[4], pbl[4];
  uint4 ar[2][4][2];
  LD_B(0, pbh, pbl); ST_B(0, pbh, pbl);
  LD_A(0, ar[0]);
  LD_A(1, ar[1]);
  LD_B(1, pbh, pbl);
  __syncthreads();

  for (int c = 0; c < 64; ++c){
    const int cur = c & 1;
    #pragma unroll
    for (int ks = 0; ks < 2; ++ks){
      U16x8 bh[4], bl[4];
      #pragma unroll
      for (int tn = 0; tn < 4; ++tn){
        const int row = wn*64 + tn*16 + l16;
        const int gk = ks*4 + quad;
        const int phys = gk ^ (row & 7);
        bh[tn].u4 = *(const uint4*)&BH[cur][row*64 + phys*8];
        bl[tn].u4 = *(const uint4*)&BL[cur][row*64 + phys*8];
      }
      #pragma unroll
      for (int tm = 0; tm < 4; ++tm){
        U16x8 a; a.u4 = ar[cur][tm][ks];
        #pragma unroll
        for (int tn = 0; tn < 4; ++tn){
          acc[tm][tn] = MFMA16(a, bh[tn], acc[tm][tn]);
          acc[tm][tn] = MFMA16(a, bl[tn], acc[tm][tn]);
        }
      }
    }
    if (c + 2 < 64) LD_A(c+2, ar[cur]);
    if (c + 1 < 64){
      ST_B(cur ^ 1, pbh, pbl);
      if (c + 2 < 64) LD_B(c+2, pbh, pbl);
      __syncthreads();
    }
  }
  #pragma unroll
  for (int tm = 0; tm < 4; ++tm){
    #pragma unroll
    for (int tn = 0; tn < 4; ++tn){
      const int p = n0 + wn*64 + tn*16 + l16;
      #pragma unroll
      for (int r = 0; r < 4; ++r){
        const int rm = m0 + wm*64 + tm*16 + quad*4 + r;
        out[((size_t)(rm & 63)*128 + (rm >> 6))*512 + p] = acc[tm][tn][r];
      }
    }
  }
}

extern "C" void kernel_launch(void* const* d_in, const int* in_sizes, int n_in,
                              void* d_out, int out_size, void* d_ws, size_t ws_size,
                              hipStream_t stream) {
  const float* v    = (const float*)d_in[0];
  const float* p0   = (const float*)d_in[1];
  const float* Wini = (const float*)d_in[2];
  const float* Wih  = (const float*)d_in[3];
  const float* Whh  = (const float*)d_in[4];
  const float* Wdec = (const float*)d_in[5];
  float* out = (float*)d_out;
  char* wsb = (char*)d_ws;

  // ws layout (bytes)
  unsigned int*   bar  = (unsigned int*)(wsb + 0);          // 16 KB
  unsigned short* hHiA = (unsigned short*)(wsb + 16384);
  unsigned short* hLoA = (unsigned short*)(wsb + 540672);
  unsigned short* hHiB = (unsigned short*)(wsb + 1064960);
  unsigned short* hLoB = (unsigned short*)(wsb + 1589248);
  float*          part = (float*)(wsb + 2113536);           // 8 MB
  unsigned short* WdH  = (unsigned short*)(wsb + 10502144); // 4 MB
  unsigned short* WdL  = (unsigned short*)(wsb + 14696448); // 4 MB
  unsigned short* G    = (unsigned short*)(wsb + 18890752); // 64 MB
  // end ~86.0 MB

  hipMemsetAsync(bar, 0, 16384, stream);
  split_fp32<<<dim3(2048), dim3(256), 0, stream>>>(Wdec, WdH, WdL, 524288);
  h0_mm<<<dim3(32), dim3(512), 0, stream>>>(p0, Wini, hHiA, hLoA);
  rnn_persist<<<dim3(256), dim3(512), 0, stream>>>(Whh, v, Wih,
                                                   hHiA, hLoA, hHiB, hLoB,
                                                   part, bar, G);
  decode_g<<<dim3(64, 4), dim3(256), 0, stream>>>(G, WdH, WdL, out);
}